// Round 9
// baseline (304.997 us; speedup 1.0000x reference)
//
#include <hip/hip_runtime.h>
#include <hip/hip_bf16.h>
#include <hip/hip_fp16.h>

#define NEG_SLOPE 0.2f
#define GGRP 128
#define TOUT 10

typedef _Float16 half8 __attribute__((ext_vector_type(8)));
typedef float floatx4 __attribute__((ext_vector_type(4)));

// ---------------------------------------------------------------------------
// init: zero degree array, zero csr pad, set pool accumulator to -inf
// ---------------------------------------------------------------------------
__global__ void init_kernel(int* __restrict__ deg, float* __restrict__ gpool,
                            int* __restrict__ csr_pad, int n, int gsize) {
    int i = blockIdx.x * blockDim.x + threadIdx.x;
    if (i < n) deg[i] = 0;
    if (i < gsize) gpool[i] = -__builtin_inff();
    if (i < 64) csr_pad[i] = 0;
}

// ---------------------------------------------------------------------------
// cvt: fp32 -> fp16 for X (big), Wl0, Wr0 (small). 8 elems / thread.
// ---------------------------------------------------------------------------
__global__ void cvt_kernel(const float* __restrict__ X, _Float16* __restrict__ Xh,
                           const float* __restrict__ Wl, _Float16* __restrict__ Wlh,
                           const float* __restrict__ Wr, _Float16* __restrict__ Wrh,
                           int nx8, int nw8) {
    int i = blockIdx.x * blockDim.x + threadIdx.x;
    const float* s; _Float16* d; int j;
    if (i < nx8) { s = X; d = Xh; j = i; }
    else if (i < nx8 + nw8) { s = Wl; d = Wlh; j = i - nx8; }
    else if (i < nx8 + 2 * nw8) { s = Wr; d = Wrh; j = i - nx8 - nw8; }
    else return;
    float4 a = *(const float4*)(s + j * 8);
    float4 b = *(const float4*)(s + j * 8 + 4);
    union { _Float16 h[8]; uint4 u; } pk;
    pk.h[0] = (_Float16)a.x; pk.h[1] = (_Float16)a.y;
    pk.h[2] = (_Float16)a.z; pk.h[3] = (_Float16)a.w;
    pk.h[4] = (_Float16)b.x; pk.h[5] = (_Float16)b.y;
    pk.h[6] = (_Float16)b.z; pk.h[7] = (_Float16)b.w;
    *(uint4*)(d + j * 8) = pk.u;
}

// ---------------------------------------------------------------------------
// degree: count incoming edges per dst (4 edges / thread, int4 loads)
// ---------------------------------------------------------------------------
__global__ void degree_kernel(const int* __restrict__ dst, int* __restrict__ deg, int E) {
    int i = blockIdx.x * blockDim.x + threadIdx.x;
    int base = i * 4;
    if (base + 3 < E) {
        int4 d = *(const int4*)(dst + base);
        atomicAdd(&deg[d.x], 1); atomicAdd(&deg[d.y], 1);
        atomicAdd(&deg[d.z], 1); atomicAdd(&deg[d.w], 1);
    } else {
        for (int k = base; k < E; ++k) atomicAdd(&deg[dst[k]], 1);
    }
}

// ---------------------------------------------------------------------------
// scan A: per-block exclusive scan + block sums
// ---------------------------------------------------------------------------
__global__ __launch_bounds__(256)
void scanA_kernel(const int* __restrict__ deg, int* __restrict__ rowptr,
                  int* __restrict__ bsum, int n) {
    __shared__ int wsum[4];
    int tid = threadIdx.x, lane = tid & 63, wid = tid >> 6;
    int idx = blockIdx.x * 256 + tid;
    int v = (idx < n) ? deg[idx] : 0;
    int x = v;
    #pragma unroll
    for (int off = 1; off < 64; off <<= 1) {
        int t = __shfl_up(x, off, 64);
        if (lane >= off) x += t;
    }
    if (lane == 63) wsum[wid] = x;
    __syncthreads();
    if (tid == 0) {
        int s = 0;
        #pragma unroll
        for (int i = 0; i < 4; ++i) { int t = wsum[i]; wsum[i] = s; s += t; }
        bsum[blockIdx.x] = s;
    }
    __syncthreads();
    int excl = x - v + wsum[wid];
    if (idx < n) rowptr[idx] = excl;
}

// ---------------------------------------------------------------------------
// scan C: apply block offsets; block 0 writes rowptr[n]
// ---------------------------------------------------------------------------
__global__ __launch_bounds__(256)
void scanC_kernel(int* __restrict__ rowptr, int* __restrict__ cursor,
                  const int* __restrict__ bsum, int n, int nb) {
    __shared__ int soff_sh;
    int tid = threadIdx.x;
    int bx = blockIdx.x;
    if (tid < 64) {
        int lane = tid;
        int v = 0;
        if (lane < nb && lane < bx) v = bsum[lane];
        if (lane + 64 < nb && lane + 64 < bx) v += bsum[lane + 64];
        #pragma unroll
        for (int off = 32; off >= 1; off >>= 1) v += __shfl_xor(v, off, 64);
        if (lane == 0) soff_sh = v;
        if (bx == 0) {
            int t = 0;
            if (lane < nb) t = bsum[lane];
            if (lane + 64 < nb) t += bsum[lane + 64];
            #pragma unroll
            for (int off = 32; off >= 1; off >>= 1) t += __shfl_xor(t, off, 64);
            if (lane == 0) rowptr[n] = t;
        }
    }
    __syncthreads();
    int idx = bx * 256 + tid;
    if (idx < n) {
        int r = rowptr[idx] + soff_sh;
        rowptr[idx] = r;
        cursor[idx] = r;
    }
}

// ---------------------------------------------------------------------------
// scatter: CSR slots hold PRE-SCALED byte offsets (src * 256, fp16 rows)
// ---------------------------------------------------------------------------
__global__ void scatter_kernel(const int* __restrict__ src, const int* __restrict__ dst,
                               int* __restrict__ cursor, int* __restrict__ csr, int E) {
    int i = blockIdx.x * blockDim.x + threadIdx.x;
    int base = i * 4;
    if (base + 3 < E) {
        int4 s = *(const int4*)(src + base);
        int4 d = *(const int4*)(dst + base);
        csr[atomicAdd(&cursor[d.x], 1)] = s.x << 8;
        csr[atomicAdd(&cursor[d.y], 1)] = s.y << 8;
        csr[atomicAdd(&cursor[d.z], 1)] = s.z << 8;
        csr[atomicAdd(&cursor[d.w], 1)] = s.w << 8;
    } else {
        for (int k = base; k < E; ++k)
            csr[atomicAdd(&cursor[dst[k]], 1)] = src[k] << 8;
    }
}

// ---------------------------------------------------------------------------
// MFMA GEMM (conv0): xlh = fp16(X@Wl.T + bl), xr = X@Wr.T + br.
// fp16 inputs, fp32 accumulate via v_mfma_f32_16x16x32_f16. (r8, verified)
// ---------------------------------------------------------------------------
__global__ __launch_bounds__(256)
void gemm_mfma_kernel(const _Float16* __restrict__ Xh,
                      const _Float16* __restrict__ Wlh, const float* __restrict__ bl,
                      const _Float16* __restrict__ Wrh, const float* __restrict__ br,
                      _Float16* __restrict__ xlh, float* __restrict__ xr, int n) {
    int tid = threadIdx.x;
    int wave = tid >> 6, lane = tid & 63;
    int r0 = blockIdx.x * 64 + wave * 16;
    if (r0 >= n) return;
    int l15 = lane & 15;
    int lkg = lane >> 4;                 // 0..3
    int arow = r0 + l15; if (arow > n - 1) arow = n - 1;

    const char* xb  = (const char*)Xh;
    const char* wlb = (const char*)Wlh;
    const char* wrb = (const char*)Wrh;

    half8 a[4];
    #pragma unroll
    for (int kc = 0; kc < 4; ++kc)
        a[kc] = *(const half8*)(xb + (size_t)arow * 256 + kc * 64 + lkg * 16);

    floatx4 accL[8], accR[8];
    #pragma unroll
    for (int t = 0; t < 8; ++t) {
        accL[t] = (floatx4){0.f, 0.f, 0.f, 0.f};
        accR[t] = (floatx4){0.f, 0.f, 0.f, 0.f};
    }

    #pragma unroll
    for (int t = 0; t < 8; ++t) {
        int wrow = t * 16 + l15;         // W row = output col
        int wk = lkg * 16;
        #pragma unroll
        for (int kc = 0; kc < 4; ++kc) {
            half8 bL = *(const half8*)(wlb + (size_t)wrow * 256 + kc * 64 + wk);
            half8 bR = *(const half8*)(wrb + (size_t)wrow * 256 + kc * 64 + wk);
            accL[t] = __builtin_amdgcn_mfma_f32_16x16x32_f16(a[kc], bL, accL[t], 0, 0, 0);
            accR[t] = __builtin_amdgcn_mfma_f32_16x16x32_f16(a[kc], bR, accR[t], 0, 0, 0);
        }
    }

    #pragma unroll
    for (int j = 0; j < 4; ++j) {
        int row = r0 + lkg * 4 + j;
        if (row < n) {
            #pragma unroll
            for (int t = 0; t < 8; ++t) {
                int col = t * 16 + l15;
                float vL = accL[t][j] + bl[col];
                float vR = accR[t][j] + br[col];
                xlh[(size_t)row * 128 + col] = (_Float16)vL;
                xr[(size_t)row * 128 + col] = vR;
            }
        }
    }
}

// ---------------------------------------------------------------------------
// VALU GEMM (conv1, FIN=32): xlh (fp16) for colBlk0, xr (fp32) for colBlk1.
// ---------------------------------------------------------------------------
template <int FIN>
__global__ __launch_bounds__(256, 2)
void gemm_tile_kernel(const float* __restrict__ X,
                      const float* __restrict__ Wl, const float* __restrict__ bl,
                      const float* __restrict__ Wr, const float* __restrict__ br,
                      _Float16* __restrict__ xlh, float* __restrict__ xr,
                      int n, int nRowBlk) {
    constexpr int BK = 32, BM = 128, LDA = BM + 4;
    constexpr int NCHUNK = FIN / BK;
    __shared__ float Xs[BK][LDA];
    __shared__ float Ws[BK][LDA];
    int tid = threadIdx.x;
    int rowBlk = blockIdx.x;
    int colBlk = 0;
    if (rowBlk >= nRowBlk) { rowBlk -= nRowBlk; colBlk = 1; }
    const float* __restrict__ Wb = colBlk ? Wr : Wl;
    const float* __restrict__ bb = colBlk ? br : bl;
    int row0 = rowBlk * BM;

    int sr  = tid >> 3;
    int skq = (tid & 7) * 4;

    float4 xpre[4], wpre[4];

    auto load_pre = [&](int c) {
        int k0 = c * BK;
        #pragma unroll
        for (int i = 0; i < 4; ++i) {
            int r = sr + i * 32;
            int gr = row0 + r;
            float4 v = {0.f, 0.f, 0.f, 0.f};
            if (gr < n) v = *(const float4*)&X[(size_t)gr * FIN + k0 + skq];
            xpre[i] = v;
            wpre[i] = *(const float4*)&Wb[(size_t)r * FIN + k0 + skq];
        }
    };
    auto store_pre = [&]() {
        #pragma unroll
        for (int i = 0; i < 4; ++i) {
            int r = sr + i * 32;
            Xs[skq + 0][r] = xpre[i].x; Xs[skq + 1][r] = xpre[i].y;
            Xs[skq + 2][r] = xpre[i].z; Xs[skq + 3][r] = xpre[i].w;
            Ws[skq + 0][r] = wpre[i].x; Ws[skq + 1][r] = wpre[i].y;
            Ws[skq + 2][r] = wpre[i].z; Ws[skq + 3][r] = wpre[i].w;
        }
    };

    load_pre(0);
    store_pre();
    __syncthreads();

    int tx = tid & 15;
    int ty = tid >> 4;
    float acc[8][8];
    #pragma unroll
    for (int i = 0; i < 8; ++i)
        #pragma unroll
        for (int j = 0; j < 8; ++j) acc[i][j] = 0.f;

    #pragma unroll
    for (int c = 0; c < NCHUNK; ++c) {
        if (c + 1 < NCHUNK) load_pre(c + 1);
        #pragma unroll 8
        for (int k = 0; k < BK; ++k) {
            float4 a0 = *(const float4*)&Xs[k][ty * 8];
            float4 a1 = *(const float4*)&Xs[k][ty * 8 + 4];
            float4 b0 = *(const float4*)&Ws[k][tx * 8];
            float4 b1 = *(const float4*)&Ws[k][tx * 8 + 4];
            float av[8] = {a0.x, a0.y, a0.z, a0.w, a1.x, a1.y, a1.z, a1.w};
            float bv[8] = {b0.x, b0.y, b0.z, b0.w, b1.x, b1.y, b1.z, b1.w};
            #pragma unroll
            for (int i = 0; i < 8; ++i)
                #pragma unroll
                for (int j = 0; j < 8; ++j)
                    acc[i][j] = fmaf(av[i], bv[j], acc[i][j]);
        }
        if (c + 1 < NCHUNK) {
            __syncthreads();
            store_pre();
            __syncthreads();
        }
    }

    float bias[8];
    #pragma unroll
    for (int j = 0; j < 8; ++j) bias[j] = bb[tx * 8 + j];
    #pragma unroll
    for (int i = 0; i < 8; ++i) {
        int gr = row0 + ty * 8 + i;
        if (gr < n) {
            float v[8];
            #pragma unroll
            for (int j = 0; j < 8; ++j) v[j] = acc[i][j] + bias[j];
            if (colBlk == 0) {
                union { _Float16 h[8]; uint4 u; } pk;
                #pragma unroll
                for (int j = 0; j < 8; ++j) pk.h[j] = (_Float16)v[j];
                *(uint4*)&xlh[(size_t)gr * 128 + tx * 8] = pk.u;
            } else {
                float4 o0 = {v[0], v[1], v[2], v[3]};
                float4 o1 = {v[4], v[5], v[6], v[7]};
                *(float4*)&xr[(size_t)gr * 128 + tx * 8]     = o0;
                *(float4*)&xr[(size_t)gr * 128 + tx * 8 + 4] = o1;
            }
        }
    }
}

// ---------------------------------------------------------------------------
// Fused GATv2 conv + Linear(HD->D).
// One wave per node; 4 edge slots (16 lanes/edge, 8 feats/lane), ring-4 row
// prefetch per slot (16 rows in flight/wave), branch-free via csr zero-pad +
// cndmask-zeroed alpha for out-of-range subs. LeakyReLU = max(e, 0.2e).
// ---------------------------------------------------------------------------
__global__ __launch_bounds__(256)
void gat_fused_kernel(const _Float16* __restrict__ xlh,
                      const float* __restrict__ xr,
                      const float* __restrict__ att, const float* __restrict__ cb,
                      const float* __restrict__ lw, const float* __restrict__ lb,
                      const int* __restrict__ rowptr, const int* __restrict__ csrb,
                      float* __restrict__ out /*[n][32]*/, int n) {
    __shared__ float lws[32][132];
    __shared__ float oslot[4][128];
    int tid = threadIdx.x;
    #pragma unroll
    for (int i = 0; i < 16; ++i) {
        int idx = tid + i * 256;
        lws[idx >> 7][idx & 127] = lw[idx];
    }
    __syncthreads();

    int wid = tid >> 6, lane = tid & 63;
    int nd = blockIdx.x * 4 + wid;
    if (nd >= n) return;
    int q4  = lane >> 4;
    int l16 = lane & 15;
    int fb  = l16 * 32;                // fp32 byte offset (8 floats)
    int fbh = l16 * 16;                // fp16 byte offset (8 halves)

    const char* __restrict__ xlhb = (const char*)xlh;
    const char* __restrict__ xrb  = (const char*)xr;

    const float4 xrA = *(const float4*)(xrb + ((size_t)nd << 9) + fb);
    const float4 xrB = *(const float4*)(xrb + ((size_t)nd << 9) + fb + 16);
    const float4 atA = *(const float4*)((const char*)att + fb);
    const float4 atB = *(const float4*)((const char*)att + fb + 16);

    float4 xlsA, xlsB;
    {
        uint4 hs = *(const uint4*)(xlhb + ((size_t)nd << 8) + fbh);
        float2 s01 = __half22float2(*(const __half2*)&hs.x);
        float2 s23 = __half22float2(*(const __half2*)&hs.y);
        float2 s45 = __half22float2(*(const __half2*)&hs.z);
        float2 s67 = __half22float2(*(const __half2*)&hs.w);
        xlsA = (float4){s01.x, s01.y, s23.x, s23.y};
        xlsB = (float4){s45.x, s45.y, s67.x, s67.y};
    }

    int start = rowptr[nd], end = rowptr[nd + 1];
    float cnt = (float)(end - start + 1);

    float den;
    float accA[4], accB[4];

    // self-loop (slot 0)
    {
        float e0 = xlsA.x + xrA.x; e0 = fmaxf(e0, NEG_SLOPE * e0);
        float e1 = xlsA.y + xrA.y; e1 = fmaxf(e1, NEG_SLOPE * e1);
        float e2 = xlsA.z + xrA.z; e2 = fmaxf(e2, NEG_SLOPE * e2);
        float e3 = xlsA.w + xrA.w; e3 = fmaxf(e3, NEG_SLOPE * e3);
        float e4 = xlsB.x + xrB.x; e4 = fmaxf(e4, NEG_SLOPE * e4);
        float e5 = xlsB.y + xrB.y; e5 = fmaxf(e5, NEG_SLOPE * e5);
        float e6 = xlsB.z + xrB.z; e6 = fmaxf(e6, NEG_SLOPE * e6);
        float e7 = xlsB.w + xrB.w; e7 = fmaxf(e7, NEG_SLOPE * e7);
        float q = e0 * atA.x + e1 * atA.y + e2 * atA.z + e3 * atA.w
                + e4 * atB.x + e5 * atB.y + e6 * atB.z + e7 * atB.w;
        q += __shfl_xor(q, 1); q += __shfl_xor(q, 2);
        float a = __expf(q);
        if (q4 == 0) {
            den = a;
            accA[0] = a * xlsA.x; accA[1] = a * xlsA.y;
            accA[2] = a * xlsA.z; accA[3] = a * xlsA.w;
            accB[0] = a * xlsB.x; accB[1] = a * xlsB.y;
            accB[2] = a * xlsB.z; accB[3] = a * xlsB.w;
        } else {
            den = 0.f;
            accA[0] = accA[1] = accA[2] = accA[3] = 0.f;
            accB[0] = accB[1] = accB[2] = accB[3] = 0.f;
        }
    }

    // consume one gathered row; guard=false zeroes alpha (no-op accumulate)
    auto consume = [&](uint4 hx, bool guard) {
        float2 f01 = __half22float2(*(const __half2*)&hx.x);
        float2 f23 = __half22float2(*(const __half2*)&hx.y);
        float2 f45 = __half22float2(*(const __half2*)&hx.z);
        float2 f67 = __half22float2(*(const __half2*)&hx.w);
        float e0 = f01.x + xrA.x; e0 = fmaxf(e0, NEG_SLOPE * e0);
        float e1 = f01.y + xrA.y; e1 = fmaxf(e1, NEG_SLOPE * e1);
        float e2 = f23.x + xrA.z; e2 = fmaxf(e2, NEG_SLOPE * e2);
        float e3 = f23.y + xrA.w; e3 = fmaxf(e3, NEG_SLOPE * e3);
        float e4 = f45.x + xrB.x; e4 = fmaxf(e4, NEG_SLOPE * e4);
        float e5 = f45.y + xrB.y; e5 = fmaxf(e5, NEG_SLOPE * e5);
        float e6 = f67.x + xrB.z; e6 = fmaxf(e6, NEG_SLOPE * e6);
        float e7 = f67.y + xrB.w; e7 = fmaxf(e7, NEG_SLOPE * e7);
        float q = e0 * atA.x + e1 * atA.y + e2 * atA.z + e3 * atA.w
                + e4 * atB.x + e5 * atB.y + e6 * atB.z + e7 * atB.w;
        q += __shfl_xor(q, 1); q += __shfl_xor(q, 2);
        float a = __expf(q);
        if (!guard) a = 0.f;
        den += a;
        accA[0] = fmaf(a, f01.x, accA[0]); accA[1] = fmaf(a, f01.y, accA[1]);
        accA[2] = fmaf(a, f23.x, accA[2]); accA[3] = fmaf(a, f23.y, accA[3]);
        accB[0] = fmaf(a, f45.x, accB[0]); accB[1] = fmaf(a, f45.y, accB[1]);
        accB[2] = fmaf(a, f67.x, accB[2]); accB[3] = fmaf(a, f67.y, accB[3]);
    };

    // edges: slot q takes i = start+q, start+q+4, ...; ring-4 prefetch.
    // csr reads reach i+44 <= E+43 (< E+64 pad). Garbage rows are zeroed
    // via the guard cndmask; pad offsets point at row 0 (valid memory).
    int i = start + q4;
    int oA = csrb[i], oB = csrb[i + 4], oC = csrb[i + 8], oD = csrb[i + 12];
    uint4 pA = *(const uint4*)(xlhb + oA + fbh);
    uint4 pB = *(const uint4*)(xlhb + oB + fbh);
    uint4 pC = *(const uint4*)(xlhb + oC + fbh);
    uint4 pD = *(const uint4*)(xlhb + oD + fbh);
    oA = csrb[i + 16]; oB = csrb[i + 20]; oC = csrb[i + 24]; oD = csrb[i + 28];
    for (; i < end; i += 16) {
        uint4 c0 = pA;
        pA = *(const uint4*)(xlhb + oA + fbh); oA = csrb[i + 32];
        consume(c0, true);
        uint4 c1 = pB;
        pB = *(const uint4*)(xlhb + oB + fbh); oB = csrb[i + 36];
        consume(c1, (i + 4) < end);
        uint4 c2 = pC;
        pC = *(const uint4*)(xlhb + oC + fbh); oC = csrb[i + 40];
        consume(c2, (i + 8) < end);
        uint4 c3 = pD;
        pD = *(const uint4*)(xlhb + oD + fbh); oD = csrb[i + 44];
        consume(c3, (i + 12) < end);
    }

    // combine the four slots (xor 16, 32 preserve l16 -> same head)
    #pragma unroll
    for (int t = 0; t < 4; ++t) {
        accA[t] += __shfl_xor(accA[t], 16); accA[t] += __shfl_xor(accA[t], 32);
        accB[t] += __shfl_xor(accB[t], 16); accB[t] += __shfl_xor(accB[t], 32);
    }
    den += __shfl_xor(den, 16); den += __shfl_xor(den, 32);

    float inv = 1.0f / (den * cnt);
    if (q4 == 0) {
        const float4 cbA = *(const float4*)((const char*)cb + fb);
        const float4 cbB = *(const float4*)((const char*)cb + fb + 16);
        float4 oA4, oB4;
        oA4.x = fmaf(accA[0], inv, cbA.x); oA4.y = fmaf(accA[1], inv, cbA.y);
        oA4.z = fmaf(accA[2], inv, cbA.z); oA4.w = fmaf(accA[3], inv, cbA.w);
        oB4.x = fmaf(accB[0], inv, cbB.x); oB4.y = fmaf(accB[1], inv, cbB.y);
        oB4.z = fmaf(accB[2], inv, cbB.z); oB4.w = fmaf(accB[3], inv, cbB.w);
        *(float4*)((char*)&oslot[wid][0] + fb)      = oA4;
        *(float4*)((char*)&oslot[wid][0] + fb + 16) = oB4;
    }
    asm volatile("s_waitcnt lgkmcnt(0)" ::: "memory");

    int half = lane >> 5;
    int l32 = lane & 31;
    float y = 0.f;
    int kbase = half * 64;
    #pragma unroll
    for (int k = 0; k < 64; k += 4) {
        float4 lv = *(const float4*)&lws[l32][kbase + k];
        float4 ov = *(const float4*)&oslot[wid][kbase + k];
        y = fmaf(lv.x, ov.x, y);
        y = fmaf(lv.y, ov.y, y);
        y = fmaf(lv.z, ov.z, y);
        y = fmaf(lv.w, ov.w, y);
    }
    y += __shfl_xor(y, 32);
    if (half == 0) out[(size_t)nd * 32 + l32] = y + lb[l32];
}

// ---------------------------------------------------------------------------
// global max pool over sorted batch ids
// ---------------------------------------------------------------------------
__device__ __forceinline__ void atomicMaxFloat(float* addr, float val) {
    if (val >= 0.f) atomicMax((int*)addr, __float_as_int(val));
    else atomicMin((unsigned int*)addr, (unsigned int)__float_as_int(val));
}

__global__ void pool_kernel(const float* __restrict__ H, const int* __restrict__ batch,
                            float* __restrict__ g, int n) {
    int tid = threadIdx.x;
    int dim = tid & 31;
    int sub = tid >> 5;
    int nodeStart = blockIdx.x * 128 + sub * 16;
    float m = -__builtin_inff();
    int cur = -1;
    for (int j = 0; j < 16; ++j) {
        int nd = nodeStart + j;
        if (nd >= n) break;
        int b = batch[nd];
        if (b != cur) {
            if (cur >= 0) atomicMaxFloat(&g[cur * 32 + dim], m);
            cur = b; m = -__builtin_inff();
        }
        m = fmaxf(m, H[nd * 32 + dim]);
    }
    if (cur >= 0) atomicMaxFloat(&g[cur * 32 + dim], m);
}

// ---------------------------------------------------------------------------
// final MLP
// ---------------------------------------------------------------------------
__global__ __launch_bounds__(256)
void fc_kernel(const float* __restrict__ g,
               const float* __restrict__ fc1W, const float* __restrict__ fc1b,
               const float* __restrict__ fc2W, const float* __restrict__ fc2b,
               float* __restrict__ out) {
    __shared__ float g1[GGRP * 32];
    int tid = threadIdx.x;
    for (int idx = tid; idx < GGRP * 32; idx += 256) {
        int r = idx >> 5, c = idx & 31;
        float acc = fc1b[c];
        #pragma unroll
        for (int k = 0; k < 32; ++k) acc = fmaf(g[r * 32 + k], fc1W[c * 32 + k], acc);
        g1[idx] = acc > 0.f ? acc : 0.f;
    }
    __syncthreads();
    for (int idx = tid; idx < GGRP * TOUT; idx += 256) {
        int r = idx / TOUT, c = idx - r * TOUT;
        float acc = fc2b[c];
        #pragma unroll
        for (int k = 0; k < 32; ++k) acc = fmaf(g1[r * 32 + k], fc2W[c * 32 + k], acc);
        out[idx] = acc;
    }
}

// ---------------------------------------------------------------------------
extern "C" void kernel_launch(void* const* d_in, const int* in_sizes, int n_in,
                              void* d_out, int out_size, void* d_ws, size_t ws_size,
                              hipStream_t stream) {
    const float* x     = (const float*)d_in[0];
    const int*   ei    = (const int*)d_in[1];
    const int*   batch = (const int*)d_in[2];
    const float* Wl0 = (const float*)d_in[3];
    const float* bl0 = (const float*)d_in[4];
    const float* Wr0 = (const float*)d_in[5];
    const float* br0 = (const float*)d_in[6];
    const float* at0 = (const float*)d_in[7];
    const float* cb0 = (const float*)d_in[8];
    const float* lw0 = (const float*)d_in[9];
    const float* lb0 = (const float*)d_in[10];
    const float* Wl1 = (const float*)d_in[11];
    const float* bl1 = (const float*)d_in[12];
    const float* Wr1 = (const float*)d_in[13];
    const float* br1 = (const float*)d_in[14];
    const float* at1 = (const float*)d_in[15];
    const float* cb1 = (const float*)d_in[16];
    const float* lw1 = (const float*)d_in[17];
    const float* lb1 = (const float*)d_in[18];
    const float* fc1W = (const float*)d_in[19];
    const float* fc1b = (const float*)d_in[20];
    const float* fc2W = (const float*)d_in[21];
    const float* fc2b = (const float*)d_in[22];

    const int n = in_sizes[0] / 128;      // 30000
    const int E = in_sizes[1] / 2;        // 480000
    const int* src = ei;
    const int* dst = ei + E;
    const int nblkScan = (n + 255) / 256; // 118
    const int nRowBlk = (n + 127) / 128;  // 235
    const int E4 = (E + 3) / 4;
    const int nx8 = n * 16;
    const int nw8 = 128 * 128 / 8;

    size_t off = 0;
    auto alloc = [&](size_t bytes) {
        void* p = (char*)d_ws + off;
        off += (bytes + 255) & ~(size_t)255;
        return p;
    };
    _Float16* xh  = (_Float16*)alloc((size_t)n * 128 * 2);
    _Float16* wlh = (_Float16*)alloc(128 * 128 * 2);
    _Float16* wrh = (_Float16*)alloc(128 * 128 * 2);
    _Float16* xlh = (_Float16*)alloc((size_t)n * 128 * 2);
    float* xr    = (float*)alloc((size_t)n * 128 * 4);
    float* hbuf  = (float*)alloc((size_t)n * 32 * 4);
    int* deg     = (int*)alloc((size_t)n * 4);
    int* rowptr  = (int*)alloc((size_t)(n + 1) * 4);
    int* cursor  = (int*)alloc((size_t)n * 4);
    int* csr     = (int*)alloc((size_t)(E + 64) * 4);
    int* bsum    = (int*)alloc(128 * 4);
    float* gpool = (float*)alloc((size_t)GGRP * 32 * 4);

    // graph structure + fp16 casts
    init_kernel<<<(n + 255) / 256, 256, 0, stream>>>(deg, gpool, csr + E, n, GGRP * 32);
    cvt_kernel<<<(nx8 + 2 * nw8 + 255) / 256, 256, 0, stream>>>(x, xh, Wl0, wlh,
                                                                Wr0, wrh, nx8, nw8);
    degree_kernel<<<(E4 + 255) / 256, 256, 0, stream>>>(dst, deg, E);
    scanA_kernel<<<nblkScan, 256, 0, stream>>>(deg, rowptr, bsum, n);
    scanC_kernel<<<nblkScan, 256, 0, stream>>>(rowptr, cursor, bsum, n, nblkScan);
    scatter_kernel<<<(E4 + 255) / 256, 256, 0, stream>>>(src, dst, cursor, csr, E);

    // conv 0: MFMA gemm + fused gat/linear
    gemm_mfma_kernel<<<(n + 63) / 64, 256, 0, stream>>>(xh, wlh, bl0, wrh, br0,
                                                        xlh, xr, n);
    gat_fused_kernel<<<(n + 3) / 4, 256, 0, stream>>>(xlh, xr, at0, cb0, lw0, lb0,
                                                      rowptr, csr, hbuf, n);
    // conv 1: VALU gemm (K=32) + fused gat/linear
    gemm_tile_kernel<32><<<2 * nRowBlk, 256, 0, stream>>>(hbuf, Wl1, bl1, Wr1, br1,
                                                          xlh, xr, n, nRowBlk);
    gat_fused_kernel<<<(n + 3) / 4, 256, 0, stream>>>(xlh, xr, at1, cb1, lw1, lb1,
                                                      rowptr, csr, hbuf, n);

    // pool + MLP
    pool_kernel<<<(n + 127) / 128, 256, 0, stream>>>(hbuf, batch, gpool, n);
    fc_kernel<<<1, 256, 0, stream>>>(gpool, fc1W, fc1b, fc2W, fc2b, (float*)d_out);
}

// Round 10
// 289.224 us; speedup vs baseline: 1.0545x; 1.0545x over previous
//
#include <hip/hip_runtime.h>
#include <hip/hip_bf16.h>
#include <hip/hip_fp16.h>

#define NEG_SLOPE 0.2f
#define GGRP 128
#define TOUT 10

typedef _Float16 half8 __attribute__((ext_vector_type(8)));
typedef float floatx4 __attribute__((ext_vector_type(4)));

// ---------------------------------------------------------------------------
// init: zero degree array, zero csr pad, set pool accumulator to -inf
// ---------------------------------------------------------------------------
__global__ void init_kernel(int* __restrict__ deg, float* __restrict__ gpool,
                            int* __restrict__ csr_pad, int n, int gsize) {
    int i = blockIdx.x * blockDim.x + threadIdx.x;
    if (i < n) deg[i] = 0;
    if (i < gsize) gpool[i] = -__builtin_inff();
    if (i < 64) csr_pad[i] = 0;
}

// ---------------------------------------------------------------------------
// cvt: fp32 -> fp16 for X, Wl0, Wr0, Wl1, Wr1. 8 elems / thread.
// ---------------------------------------------------------------------------
__global__ void cvt_kernel(const float* __restrict__ X, _Float16* __restrict__ Xh,
                           const float* __restrict__ Wl0, _Float16* __restrict__ Wl0h,
                           const float* __restrict__ Wr0, _Float16* __restrict__ Wr0h,
                           const float* __restrict__ Wl1, _Float16* __restrict__ Wl1h,
                           const float* __restrict__ Wr1, _Float16* __restrict__ Wr1h,
                           int nx8, int nw8, int nw1) {
    int i = blockIdx.x * blockDim.x + threadIdx.x;
    const float* s; _Float16* d; int j;
    if (i < nx8) { s = X; d = Xh; j = i; }
    else if (i < nx8 + nw8) { s = Wl0; d = Wl0h; j = i - nx8; }
    else if (i < nx8 + 2 * nw8) { s = Wr0; d = Wr0h; j = i - nx8 - nw8; }
    else if (i < nx8 + 2 * nw8 + nw1) { s = Wl1; d = Wl1h; j = i - nx8 - 2 * nw8; }
    else if (i < nx8 + 2 * nw8 + 2 * nw1) { s = Wr1; d = Wr1h; j = i - nx8 - 2 * nw8 - nw1; }
    else return;
    float4 a = *(const float4*)(s + j * 8);
    float4 b = *(const float4*)(s + j * 8 + 4);
    union { _Float16 h[8]; uint4 u; } pk;
    pk.h[0] = (_Float16)a.x; pk.h[1] = (_Float16)a.y;
    pk.h[2] = (_Float16)a.z; pk.h[3] = (_Float16)a.w;
    pk.h[4] = (_Float16)b.x; pk.h[5] = (_Float16)b.y;
    pk.h[6] = (_Float16)b.z; pk.h[7] = (_Float16)b.w;
    *(uint4*)(d + j * 8) = pk.u;
}

// ---------------------------------------------------------------------------
// degree: count incoming edges per dst (4 edges / thread, int4 loads)
// ---------------------------------------------------------------------------
__global__ void degree_kernel(const int* __restrict__ dst, int* __restrict__ deg, int E) {
    int i = blockIdx.x * blockDim.x + threadIdx.x;
    int base = i * 4;
    if (base + 3 < E) {
        int4 d = *(const int4*)(dst + base);
        atomicAdd(&deg[d.x], 1); atomicAdd(&deg[d.y], 1);
        atomicAdd(&deg[d.z], 1); atomicAdd(&deg[d.w], 1);
    } else {
        for (int k = base; k < E; ++k) atomicAdd(&deg[dst[k]], 1);
    }
}

// ---------------------------------------------------------------------------
// scan A: per-block exclusive scan + block sums
// ---------------------------------------------------------------------------
__global__ __launch_bounds__(256)
void scanA_kernel(const int* __restrict__ deg, int* __restrict__ rowptr,
                  int* __restrict__ bsum, int n) {
    __shared__ int wsum[4];
    int tid = threadIdx.x, lane = tid & 63, wid = tid >> 6;
    int idx = blockIdx.x * 256 + tid;
    int v = (idx < n) ? deg[idx] : 0;
    int x = v;
    #pragma unroll
    for (int off = 1; off < 64; off <<= 1) {
        int t = __shfl_up(x, off, 64);
        if (lane >= off) x += t;
    }
    if (lane == 63) wsum[wid] = x;
    __syncthreads();
    if (tid == 0) {
        int s = 0;
        #pragma unroll
        for (int i = 0; i < 4; ++i) { int t = wsum[i]; wsum[i] = s; s += t; }
        bsum[blockIdx.x] = s;
    }
    __syncthreads();
    int excl = x - v + wsum[wid];
    if (idx < n) rowptr[idx] = excl;
}

// ---------------------------------------------------------------------------
// scan C: apply block offsets; block 0 writes rowptr[n]
// ---------------------------------------------------------------------------
__global__ __launch_bounds__(256)
void scanC_kernel(int* __restrict__ rowptr, int* __restrict__ cursor,
                  const int* __restrict__ bsum, int n, int nb) {
    __shared__ int soff_sh;
    int tid = threadIdx.x;
    int bx = blockIdx.x;
    if (tid < 64) {
        int lane = tid;
        int v = 0;
        if (lane < nb && lane < bx) v = bsum[lane];
        if (lane + 64 < nb && lane + 64 < bx) v += bsum[lane + 64];
        #pragma unroll
        for (int off = 32; off >= 1; off >>= 1) v += __shfl_xor(v, off, 64);
        if (lane == 0) soff_sh = v;
        if (bx == 0) {
            int t = 0;
            if (lane < nb) t = bsum[lane];
            if (lane + 64 < nb) t += bsum[lane + 64];
            #pragma unroll
            for (int off = 32; off >= 1; off >>= 1) t += __shfl_xor(t, off, 64);
            if (lane == 0) rowptr[n] = t;
        }
    }
    __syncthreads();
    int idx = bx * 256 + tid;
    if (idx < n) {
        int r = rowptr[idx] + soff_sh;
        rowptr[idx] = r;
        cursor[idx] = r;
    }
}

// ---------------------------------------------------------------------------
// scatter: CSR slots hold PRE-SCALED byte offsets (src * 256, fp16 rows)
// ---------------------------------------------------------------------------
__global__ void scatter_kernel(const int* __restrict__ src, const int* __restrict__ dst,
                               int* __restrict__ cursor, int* __restrict__ csr, int E) {
    int i = blockIdx.x * blockDim.x + threadIdx.x;
    int base = i * 4;
    if (base + 3 < E) {
        int4 s = *(const int4*)(src + base);
        int4 d = *(const int4*)(dst + base);
        csr[atomicAdd(&cursor[d.x], 1)] = s.x << 8;
        csr[atomicAdd(&cursor[d.y], 1)] = s.y << 8;
        csr[atomicAdd(&cursor[d.z], 1)] = s.z << 8;
        csr[atomicAdd(&cursor[d.w], 1)] = s.w << 8;
    } else {
        for (int k = base; k < E; ++k)
            csr[atomicAdd(&cursor[dst[k]], 1)] = src[k] << 8;
    }
}

// ---------------------------------------------------------------------------
// MFMA GEMM (conv0, K=128): xlh = fp16(X@Wl.T + bl), xr = X@Wr.T + br.
// fp16 inputs, fp32 accumulate via v_mfma_f32_16x16x32_f16. (r8, verified)
// ---------------------------------------------------------------------------
__global__ __launch_bounds__(256)
void gemm_mfma_kernel(const _Float16* __restrict__ Xh,
                      const _Float16* __restrict__ Wlh, const float* __restrict__ bl,
                      const _Float16* __restrict__ Wrh, const float* __restrict__ br,
                      _Float16* __restrict__ xlh, float* __restrict__ xr, int n) {
    int tid = threadIdx.x;
    int wave = tid >> 6, lane = tid & 63;
    int r0 = blockIdx.x * 64 + wave * 16;
    if (r0 >= n) return;
    int l15 = lane & 15;
    int lkg = lane >> 4;                 // 0..3
    int arow = r0 + l15; if (arow > n - 1) arow = n - 1;

    const char* xb  = (const char*)Xh;
    const char* wlb = (const char*)Wlh;
    const char* wrb = (const char*)Wrh;

    half8 a[4];
    #pragma unroll
    for (int kc = 0; kc < 4; ++kc)
        a[kc] = *(const half8*)(xb + (size_t)arow * 256 + kc * 64 + lkg * 16);

    floatx4 accL[8], accR[8];
    #pragma unroll
    for (int t = 0; t < 8; ++t) {
        accL[t] = (floatx4){0.f, 0.f, 0.f, 0.f};
        accR[t] = (floatx4){0.f, 0.f, 0.f, 0.f};
    }

    #pragma unroll
    for (int t = 0; t < 8; ++t) {
        int wrow = t * 16 + l15;         // W row = output col
        int wk = lkg * 16;
        #pragma unroll
        for (int kc = 0; kc < 4; ++kc) {
            half8 bL = *(const half8*)(wlb + (size_t)wrow * 256 + kc * 64 + wk);
            half8 bR = *(const half8*)(wrb + (size_t)wrow * 256 + kc * 64 + wk);
            accL[t] = __builtin_amdgcn_mfma_f32_16x16x32_f16(a[kc], bL, accL[t], 0, 0, 0);
            accR[t] = __builtin_amdgcn_mfma_f32_16x16x32_f16(a[kc], bR, accR[t], 0, 0, 0);
        }
    }

    #pragma unroll
    for (int j = 0; j < 4; ++j) {
        int row = r0 + lkg * 4 + j;
        if (row < n) {
            #pragma unroll
            for (int t = 0; t < 8; ++t) {
                int col = t * 16 + l15;
                float vL = accL[t][j] + bl[col];
                float vR = accR[t][j] + br[col];
                xlh[(size_t)row * 128 + col] = (_Float16)vL;
                xr[(size_t)row * 128 + col] = vR;
            }
        }
    }
}

// ---------------------------------------------------------------------------
// MFMA GEMM (conv1, K=32): reads fp16 H [n][32]; one mfma per 16x16 tile.
// Same fragment layout as gemm_mfma_kernel.
// ---------------------------------------------------------------------------
__global__ __launch_bounds__(256)
void gemm_mfma32_kernel(const _Float16* __restrict__ Hh,
                        const _Float16* __restrict__ Wlh, const float* __restrict__ bl,
                        const _Float16* __restrict__ Wrh, const float* __restrict__ br,
                        _Float16* __restrict__ xlh, float* __restrict__ xr, int n) {
    int tid = threadIdx.x;
    int wave = tid >> 6, lane = tid & 63;
    int r0 = blockIdx.x * 64 + wave * 16;
    if (r0 >= n) return;
    int l15 = lane & 15;
    int lkg = lane >> 4;                 // 0..3
    int arow = r0 + l15; if (arow > n - 1) arow = n - 1;

    half8 a = *(const half8*)(Hh + (size_t)arow * 32 + lkg * 8);

    floatx4 accL[8], accR[8];
    #pragma unroll
    for (int t = 0; t < 8; ++t) {
        int wrow = t * 16 + l15;         // W row = output col
        half8 bL = *(const half8*)(Wlh + (size_t)wrow * 32 + lkg * 8);
        half8 bR = *(const half8*)(Wrh + (size_t)wrow * 32 + lkg * 8);
        floatx4 z = (floatx4){0.f, 0.f, 0.f, 0.f};
        accL[t] = __builtin_amdgcn_mfma_f32_16x16x32_f16(a, bL, z, 0, 0, 0);
        accR[t] = __builtin_amdgcn_mfma_f32_16x16x32_f16(a, bR, z, 0, 0, 0);
    }

    #pragma unroll
    for (int j = 0; j < 4; ++j) {
        int row = r0 + lkg * 4 + j;
        if (row < n) {
            #pragma unroll
            for (int t = 0; t < 8; ++t) {
                int col = t * 16 + l15;
                float vL = accL[t][j] + bl[col];
                float vR = accR[t][j] + br[col];
                xlh[(size_t)row * 128 + col] = (_Float16)vL;
                xr[(size_t)row * 128 + col] = vR;
            }
        }
    }
}

// ---------------------------------------------------------------------------
// Fused GATv2 conv + Linear(HD->D).  (r8 depth-2 structure, reverted)
// One wave per node; 4 edge slots (16 lanes/edge, 8 feats/lane), depth-2
// ping-pong prefetch, branch-free via csr zero-pad.
// Epilogue also emits fp16 copy of the output (for conv1's MFMA GEMM).
// ---------------------------------------------------------------------------
__global__ __launch_bounds__(256)
void gat_fused_kernel(const _Float16* __restrict__ xlh,
                      const float* __restrict__ xr,
                      const float* __restrict__ att, const float* __restrict__ cb,
                      const float* __restrict__ lw, const float* __restrict__ lb,
                      const int* __restrict__ rowptr, const int* __restrict__ csrb,
                      float* __restrict__ out /*[n][32]*/,
                      _Float16* __restrict__ outh /*[n][32]*/, int n) {
    __shared__ float lws[32][132];
    __shared__ float oslot[4][128];
    int tid = threadIdx.x;
    #pragma unroll
    for (int i = 0; i < 16; ++i) {
        int idx = tid + i * 256;
        lws[idx >> 7][idx & 127] = lw[idx];
    }
    __syncthreads();

    int wid = tid >> 6, lane = tid & 63;
    int nd = blockIdx.x * 4 + wid;
    if (nd >= n) return;
    int q4  = lane >> 4;
    int l16 = lane & 15;
    int fb  = l16 * 32;                // fp32 byte offset (8 floats)
    int fbh = l16 * 16;                // fp16 byte offset (8 halves)

    const char* __restrict__ xlhb = (const char*)xlh;
    const char* __restrict__ xrb  = (const char*)xr;

    const float4 xrA = *(const float4*)(xrb + ((size_t)nd << 9) + fb);
    const float4 xrB = *(const float4*)(xrb + ((size_t)nd << 9) + fb + 16);
    const float4 atA = *(const float4*)((const char*)att + fb);
    const float4 atB = *(const float4*)((const char*)att + fb + 16);

    float4 xlsA, xlsB;
    {
        uint4 hs = *(const uint4*)(xlhb + ((size_t)nd << 8) + fbh);
        float2 s01 = __half22float2(*(const __half2*)&hs.x);
        float2 s23 = __half22float2(*(const __half2*)&hs.y);
        float2 s45 = __half22float2(*(const __half2*)&hs.z);
        float2 s67 = __half22float2(*(const __half2*)&hs.w);
        xlsA = (float4){s01.x, s01.y, s23.x, s23.y};
        xlsB = (float4){s45.x, s45.y, s67.x, s67.y};
    }

    int start = rowptr[nd], end = rowptr[nd + 1];
    float cnt = (float)(end - start + 1);

    float den;
    float accA[4], accB[4];

    // self-loop (slot 0)
    {
        float e0 = xlsA.x + xrA.x; e0 = fmaxf(e0, NEG_SLOPE * e0);
        float e1 = xlsA.y + xrA.y; e1 = fmaxf(e1, NEG_SLOPE * e1);
        float e2 = xlsA.z + xrA.z; e2 = fmaxf(e2, NEG_SLOPE * e2);
        float e3 = xlsA.w + xrA.w; e3 = fmaxf(e3, NEG_SLOPE * e3);
        float e4 = xlsB.x + xrB.x; e4 = fmaxf(e4, NEG_SLOPE * e4);
        float e5 = xlsB.y + xrB.y; e5 = fmaxf(e5, NEG_SLOPE * e5);
        float e6 = xlsB.z + xrB.z; e6 = fmaxf(e6, NEG_SLOPE * e6);
        float e7 = xlsB.w + xrB.w; e7 = fmaxf(e7, NEG_SLOPE * e7);
        float q = e0 * atA.x + e1 * atA.y + e2 * atA.z + e3 * atA.w
                + e4 * atB.x + e5 * atB.y + e6 * atB.z + e7 * atB.w;
        q += __shfl_xor(q, 1); q += __shfl_xor(q, 2);
        float a = __expf(q);
        if (q4 == 0) {
            den = a;
            accA[0] = a * xlsA.x; accA[1] = a * xlsA.y;
            accA[2] = a * xlsA.z; accA[3] = a * xlsA.w;
            accB[0] = a * xlsB.x; accB[1] = a * xlsB.y;
            accB[2] = a * xlsB.z; accB[3] = a * xlsB.w;
        } else {
            den = 0.f;
            accA[0] = accA[1] = accA[2] = accA[3] = 0.f;
            accB[0] = accB[1] = accB[2] = accB[3] = 0.f;
        }
    }

    // edges: slot q takes i = start+q, start+q+4, ...; depth-2 ping-pong.
    int i = start + q4;
    int offC = csrb[i + 8];
    uint4 preA = *(const uint4*)(xlhb + csrb[i] + fbh);
    uint4 preB = *(const uint4*)(xlhb + csrb[i + 4] + fbh);
    for (; i < end; i += 4) {
        uint4 hx = preA;
        preA = preB;
        preB = *(const uint4*)(xlhb + offC + fbh);
        offC = csrb[i + 12];
        float2 f01 = __half22float2(*(const __half2*)&hx.x);
        float2 f23 = __half22float2(*(const __half2*)&hx.y);
        float2 f45 = __half22float2(*(const __half2*)&hx.z);
        float2 f67 = __half22float2(*(const __half2*)&hx.w);
        float e0 = f01.x + xrA.x; e0 = fmaxf(e0, NEG_SLOPE * e0);
        float e1 = f01.y + xrA.y; e1 = fmaxf(e1, NEG_SLOPE * e1);
        float e2 = f23.x + xrA.z; e2 = fmaxf(e2, NEG_SLOPE * e2);
        float e3 = f23.y + xrA.w; e3 = fmaxf(e3, NEG_SLOPE * e3);
        float e4 = f45.x + xrB.x; e4 = fmaxf(e4, NEG_SLOPE * e4);
        float e5 = f45.y + xrB.y; e5 = fmaxf(e5, NEG_SLOPE * e5);
        float e6 = f67.x + xrB.z; e6 = fmaxf(e6, NEG_SLOPE * e6);
        float e7 = f67.y + xrB.w; e7 = fmaxf(e7, NEG_SLOPE * e7);
        float q = e0 * atA.x + e1 * atA.y + e2 * atA.z + e3 * atA.w
                + e4 * atB.x + e5 * atB.y + e6 * atB.z + e7 * atB.w;
        q += __shfl_xor(q, 1); q += __shfl_xor(q, 2);
        float a = __expf(q);
        den += a;
        accA[0] = fmaf(a, f01.x, accA[0]); accA[1] = fmaf(a, f01.y, accA[1]);
        accA[2] = fmaf(a, f23.x, accA[2]); accA[3] = fmaf(a, f23.y, accA[3]);
        accB[0] = fmaf(a, f45.x, accB[0]); accB[1] = fmaf(a, f45.y, accB[1]);
        accB[2] = fmaf(a, f67.x, accB[2]); accB[3] = fmaf(a, f67.y, accB[3]);
    }

    // combine the four slots (xor 16, 32 preserve l16 -> same head)
    #pragma unroll
    for (int t = 0; t < 4; ++t) {
        accA[t] += __shfl_xor(accA[t], 16); accA[t] += __shfl_xor(accA[t], 32);
        accB[t] += __shfl_xor(accB[t], 16); accB[t] += __shfl_xor(accB[t], 32);
    }
    den += __shfl_xor(den, 16); den += __shfl_xor(den, 32);

    float inv = 1.0f / (den * cnt);
    if (q4 == 0) {
        const float4 cbA = *(const float4*)((const char*)cb + fb);
        const float4 cbB = *(const float4*)((const char*)cb + fb + 16);
        float4 oA4, oB4;
        oA4.x = fmaf(accA[0], inv, cbA.x); oA4.y = fmaf(accA[1], inv, cbA.y);
        oA4.z = fmaf(accA[2], inv, cbA.z); oA4.w = fmaf(accA[3], inv, cbA.w);
        oB4.x = fmaf(accB[0], inv, cbB.x); oB4.y = fmaf(accB[1], inv, cbB.y);
        oB4.z = fmaf(accB[2], inv, cbB.z); oB4.w = fmaf(accB[3], inv, cbB.w);
        *(float4*)((char*)&oslot[wid][0] + fb)      = oA4;
        *(float4*)((char*)&oslot[wid][0] + fb + 16) = oB4;
    }
    asm volatile("s_waitcnt lgkmcnt(0)" ::: "memory");

    int half = lane >> 5;
    int l32 = lane & 31;
    float y = 0.f;
    int kbase = half * 64;
    #pragma unroll
    for (int k = 0; k < 64; k += 4) {
        float4 lv = *(const float4*)&lws[l32][kbase + k];
        float4 ov = *(const float4*)&oslot[wid][kbase + k];
        y = fmaf(lv.x, ov.x, y);
        y = fmaf(lv.y, ov.y, y);
        y = fmaf(lv.z, ov.z, y);
        y = fmaf(lv.w, ov.w, y);
    }
    y += __shfl_xor(y, 32);
    if (half == 0) {
        float yy = y + lb[l32];
        out[(size_t)nd * 32 + l32] = yy;
        outh[(size_t)nd * 32 + l32] = (_Float16)yy;
    }
}

// ---------------------------------------------------------------------------
// global max pool over sorted batch ids
// ---------------------------------------------------------------------------
__device__ __forceinline__ void atomicMaxFloat(float* addr, float val) {
    if (val >= 0.f) atomicMax((int*)addr, __float_as_int(val));
    else atomicMin((unsigned int*)addr, (unsigned int)__float_as_int(val));
}

__global__ void pool_kernel(const float* __restrict__ H, const int* __restrict__ batch,
                            float* __restrict__ g, int n) {
    int tid = threadIdx.x;
    int dim = tid & 31;
    int sub = tid >> 5;
    int nodeStart = blockIdx.x * 128 + sub * 16;
    float m = -__builtin_inff();
    int cur = -1;
    for (int j = 0; j < 16; ++j) {
        int nd = nodeStart + j;
        if (nd >= n) break;
        int b = batch[nd];
        if (b != cur) {
            if (cur >= 0) atomicMaxFloat(&g[cur * 32 + dim], m);
            cur = b; m = -__builtin_inff();
        }
        m = fmaxf(m, H[nd * 32 + dim]);
    }
    if (cur >= 0) atomicMaxFloat(&g[cur * 32 + dim], m);
}

// ---------------------------------------------------------------------------
// final MLP
// ---------------------------------------------------------------------------
__global__ __launch_bounds__(256)
void fc_kernel(const float* __restrict__ g,
               const float* __restrict__ fc1W, const float* __restrict__ fc1b,
               const float* __restrict__ fc2W, const float* __restrict__ fc2b,
               float* __restrict__ out) {
    __shared__ float g1[GGRP * 32];
    int tid = threadIdx.x;
    for (int idx = tid; idx < GGRP * 32; idx += 256) {
        int r = idx >> 5, c = idx & 31;
        float acc = fc1b[c];
        #pragma unroll
        for (int k = 0; k < 32; ++k) acc = fmaf(g[r * 32 + k], fc1W[c * 32 + k], acc);
        g1[idx] = acc > 0.f ? acc : 0.f;
    }
    __syncthreads();
    for (int idx = tid; idx < GGRP * TOUT; idx += 256) {
        int r = idx / TOUT, c = idx - r * TOUT;
        float acc = fc2b[c];
        #pragma unroll
        for (int k = 0; k < 32; ++k) acc = fmaf(g1[r * 32 + k], fc2W[c * 32 + k], acc);
        out[idx] = acc;
    }
}

// ---------------------------------------------------------------------------
extern "C" void kernel_launch(void* const* d_in, const int* in_sizes, int n_in,
                              void* d_out, int out_size, void* d_ws, size_t ws_size,
                              hipStream_t stream) {
    const float* x     = (const float*)d_in[0];
    const int*   ei    = (const int*)d_in[1];
    const int*   batch = (const int*)d_in[2];
    const float* Wl0 = (const float*)d_in[3];
    const float* bl0 = (const float*)d_in[4];
    const float* Wr0 = (const float*)d_in[5];
    const float* br0 = (const float*)d_in[6];
    const float* at0 = (const float*)d_in[7];
    const float* cb0 = (const float*)d_in[8];
    const float* lw0 = (const float*)d_in[9];
    const float* lb0 = (const float*)d_in[10];
    const float* Wl1 = (const float*)d_in[11];
    const float* bl1 = (const float*)d_in[12];
    const float* Wr1 = (const float*)d_in[13];
    const float* br1 = (const float*)d_in[14];
    const float* at1 = (const float*)d_in[15];
    const float* cb1 = (const float*)d_in[16];
    const float* lw1 = (const float*)d_in[17];
    const float* lb1 = (const float*)d_in[18];
    const float* fc1W = (const float*)d_in[19];
    const float* fc1b = (const float*)d_in[20];
    const float* fc2W = (const float*)d_in[21];
    const float* fc2b = (const float*)d_in[22];

    const int n = in_sizes[0] / 128;      // 30000
    const int E = in_sizes[1] / 2;        // 480000
    const int* src = ei;
    const int* dst = ei + E;
    const int nblkScan = (n + 255) / 256; // 118
    const int E4 = (E + 3) / 4;
    const int nx8 = n * 16;               // X fp16-groups of 8
    const int nw8 = 128 * 128 / 8;        // 2048 per conv0 W
    const int nw1 = 128 * 32 / 8;         // 512 per conv1 W

    size_t off = 0;
    auto alloc = [&](size_t bytes) {
        void* p = (char*)d_ws + off;
        off += (bytes + 255) & ~(size_t)255;
        return p;
    };
    _Float16* xh   = (_Float16*)alloc((size_t)n * 128 * 2);
    _Float16* wl0h = (_Float16*)alloc(128 * 128 * 2);
    _Float16* wr0h = (_Float16*)alloc(128 * 128 * 2);
    _Float16* wl1h = (_Float16*)alloc(128 * 32 * 2);
    _Float16* wr1h = (_Float16*)alloc(128 * 32 * 2);
    _Float16* xlh  = (_Float16*)alloc((size_t)n * 128 * 2);
    float* xr    = (float*)alloc((size_t)n * 128 * 4);
    float* hbuf  = (float*)alloc((size_t)n * 32 * 4);
    _Float16* hbufh = (_Float16*)alloc((size_t)n * 32 * 2);
    int* deg     = (int*)alloc((size_t)n * 4);
    int* rowptr  = (int*)alloc((size_t)(n + 1) * 4);
    int* cursor  = (int*)alloc((size_t)n * 4);
    int* csr     = (int*)alloc((size_t)(E + 64) * 4);
    int* bsum    = (int*)alloc(128 * 4);
    float* gpool = (float*)alloc((size_t)GGRP * 32 * 4);

    // graph structure + fp16 casts
    init_kernel<<<(n + 255) / 256, 256, 0, stream>>>(deg, gpool, csr + E, n, GGRP * 32);
    cvt_kernel<<<(nx8 + 2 * nw8 + 2 * nw1 + 255) / 256, 256, 0, stream>>>(
        x, xh, Wl0, wl0h, Wr0, wr0h, Wl1, wl1h, Wr1, wr1h, nx8, nw8, nw1);
    degree_kernel<<<(E4 + 255) / 256, 256, 0, stream>>>(dst, deg, E);
    scanA_kernel<<<nblkScan, 256, 0, stream>>>(deg, rowptr, bsum, n);
    scanC_kernel<<<nblkScan, 256, 0, stream>>>(rowptr, cursor, bsum, n, nblkScan);
    scatter_kernel<<<(E4 + 255) / 256, 256, 0, stream>>>(src, dst, cursor, csr, E);

    // conv 0: MFMA gemm (K=128) + fused gat/linear
    gemm_mfma_kernel<<<(n + 63) / 64, 256, 0, stream>>>(xh, wl0h, bl0, wr0h, br0,
                                                        xlh, xr, n);
    gat_fused_kernel<<<(n + 3) / 4, 256, 0, stream>>>(xlh, xr, at0, cb0, lw0, lb0,
                                                      rowptr, csr, hbuf, hbufh, n);
    // conv 1: MFMA gemm (K=32) + fused gat/linear
    gemm_mfma32_kernel<<<(n + 63) / 64, 256, 0, stream>>>(hbufh, wl1h, bl1, wr1h, br1,
                                                          xlh, xr, n);
    gat_fused_kernel<<<(n + 3) / 4, 256, 0, stream>>>(xlh, xr, at1, cb1, lw1, lb1,
                                                      rowptr, csr, hbuf, hbufh, n);

    // pool + MLP
    pool_kernel<<<(n + 127) / 128, 256, 0, stream>>>(hbuf, batch, gpool, n);
    fc_kernel<<<1, 256, 0, stream>>>(gpool, fc1W, fc1b, fc2W, fc2b, (float*)d_out);
}